// Round 3
// baseline (428.691 us; speedup 1.0000x reference)
//
#include <hip/hip_runtime.h>

// Problem constants (setup_inputs is fixed):
//   x:         (B=16, L=512, D=768) fp32
//   width_emb: (W=8, WD=64) fp32
//   max_width = 8; n_spans = sum_{w=1..8}(512-w+1) = 4068
//   out: (B, 4068, 1600) fp32  = 416.6 MB
constexpr uint32_t B  = 16;
constexpr uint32_t L  = 512;
constexpr uint32_t D4 = 768 / 4;   // 192 float4 per x row
constexpr uint32_t WD4 = 64 / 4;   // 16 float4 per width_emb row
constexpr uint32_t NSPANS = 4068;
constexpr uint32_t ROW_F4 = 2 * D4 + WD4;            // 400 float4 per out row
constexpr uint32_t TOTAL_F4 = B * NSPANS * ROW_F4;   // 26,035,200
constexpr uint32_t PER_THREAD = 4;
constexpr uint32_t CHUNK = TOTAL_F4 / PER_THREAD;    // 6,508,800 (exact)
constexpr uint32_t BLOCKS = CHUNK / 256;             // 25,425 (exact)

// True clang vector type — required by __builtin_nontemporal_store.
typedef float fvec4 __attribute__((ext_vector_type(4)));

__global__ __launch_bounds__(256) void span_rep_kernel(
    const fvec4* __restrict__ x4,
    const fvec4* __restrict__ w4,
    fvec4* __restrict__ out4) {
  const uint32_t tid = blockIdx.x * 256u + threadIdx.x;

  const fvec4* p[PER_THREAD];

#pragma unroll
  for (uint32_t it = 0; it < PER_THREAD; ++it) {
    const uint32_t idx = tid + it * CHUNK;

    // (row, col) in the (B*NSPANS, 400) output matrix — constant divisors.
    const uint32_t r = idx / ROW_F4;
    const uint32_t c = idx - r * ROW_F4;
    const uint32_t b = r / NSPANS;
    const uint32_t s = r - b * NSPANS;

    // Width bucket: first span index of bucket k is L*k - k(k-1)/2.
    uint32_t wid = 0;
#pragma unroll
    for (uint32_t k = 1; k < 8; ++k) {
      const uint32_t o = L * k - (k * (k - 1)) / 2;  // compile-time constant
      wid += (s >= o) ? 1u : 0u;
    }
    const uint32_t start = s - (L * wid - (wid * (wid - 1u)) / 2u);

    // Branchless source-address select: exactly one load per element.
    const bool second = (c >= D4);        // h_end segment
    const bool emb    = (c >= 2 * D4);    // width-emb segment
    const uint32_t xrow = b * L + start + (second ? wid : 0u);
    const uint32_t xcol = c - (second ? D4 : 0u);
    const fvec4* px = x4 + (xrow * D4 + xcol);
    const fvec4* pw = w4 + (wid * WD4 + (c - 2 * D4));
    p[it] = emb ? pw : px;
  }

  fvec4 v[PER_THREAD];
#pragma unroll
  for (uint32_t it = 0; it < PER_THREAD; ++it) v[it] = *p[it];  // 4 loads in flight

#pragma unroll
  for (uint32_t it = 0; it < PER_THREAD; ++it)
    __builtin_nontemporal_store(v[it], out4 + (tid + it * CHUNK));
}

extern "C" void kernel_launch(void* const* d_in, const int* in_sizes, int n_in,
                              void* d_out, int out_size, void* d_ws, size_t ws_size,
                              hipStream_t stream) {
  const fvec4* x4 = (const fvec4*)d_in[0];
  const fvec4* w4 = (const fvec4*)d_in[1];
  fvec4* out4 = (fvec4*)d_out;

  span_rep_kernel<<<dim3(BLOCKS), dim3(256), 0, stream>>>(x4, w4, out4);
}